// Round 16
// baseline (112.693 us; speedup 1.0000x reference)
//
#include <hip/hip_runtime.h>
#include <hip/hip_bf16.h>

#define NN 4096
#define IN_F 128
#define OUT_F 64
#define C_TOT 256
#define ALPHA 0.2f
#define LOG2E 1.4426950408889634f

typedef float f32x4 __attribute__((ext_vector_type(4)));
typedef float f32x2 __attribute__((ext_vector_type(2)));
typedef __bf16 bf16x8 __attribute__((ext_vector_type(8)));

__device__ __forceinline__ unsigned fmap(float f) {
    unsigned u = __float_as_uint(f);
    return (u >> 31) ? ~u : (u | 0x80000000u);
}
__device__ __forceinline__ float funmap(unsigned u) {
    return (u >> 31) ? __uint_as_float(u & 0x7FFFFFFFu) : __uint_as_float(~u);
}
__device__ __forceinline__ unsigned short bfbits(float x) {
    union { __bf16 b; unsigned short u; } t;
    t.b = (__bf16)x;
    return t.u;
}

// ---------------------------------------------------------------------------
// K1: adj -> TRANSPOSED bitmask maskT[word 0..127][row 0..4095] via ballot
// (word wi covers j = wi*32 + bit). Blocks 0..31 transpose W -> WTbf bf16;
// block 0 computes uLR=W@a, zeroes Rmax. Grid 1024 x 256.
// ---------------------------------------------------------------------------
__global__ __launch_bounds__(256) void k_mask(
    const int* __restrict__ adj, unsigned* __restrict__ maskT,
    const float* __restrict__ W, const float* __restrict__ a,
    unsigned short* __restrict__ WTbf, float* __restrict__ uLR,
    unsigned int* __restrict__ Rmax)
{
    const int tid = threadIdx.x;
    const int lane = tid & 63, wv = tid >> 6;
    const int row = blockIdx.x * 4 + wv;
    const int* __restrict__ ar = adj + (size_t)row * NN;
    for (int c = 0; c < 8; ++c) {
        const int j0 = c * 512;
        unsigned w = 0u;
#pragma unroll
        for (int k = 0; k < 8; ++k) {
            const unsigned long long bb = __ballot(ar[j0 + k * 64 + lane] > 0);
            const unsigned lo = (unsigned)bb, hi = (unsigned)(bb >> 32);
            if ((lane >> 1) == k) w = (lane & 1) ? hi : lo;
        }
        if (lane < 16) {
            const int wi = c * 16 + lane;            // word index 0..127
            maskT[(size_t)wi * NN + row] = w;        // transposed
        }
    }

    if (blockIdx.x < 32) {      // merged k_misc
        const int b = blockIdx.x;
        const int c = b * 8 + (tid & 7);
#pragma unroll
        for (int pass = 0; pass < 4; ++pass) {
            const int k = pass * 32 + (tid >> 3);
            WTbf[(size_t)c * IN_F + k] = bfbits(W[k * C_TOT + c]);
        }
        if (b == 0) {
            if (tid < 4) Rmax[tid] = 0u;
            for (int o = tid; o < 1024; o += 256) {
                const int k = o >> 3, j = o & 7;
                const int hd = j & 3, side = j >> 2;
                float s = 0.f;
                for (int f = 0; f < OUT_F; ++f)
                    s = fmaf(W[k * C_TOT + hd * OUT_F + f], a[side * OUT_F + f], s);
                uLR[k * 8 + side * 4 + hd] = s;
            }
        }
    }
}

// ---------------------------------------------------------------------------
// K2: Wh via MFMA -> WhT [256][4096] bf16; f32 left; er[hd][j]=exp2(r'),
// er2[hd][j]=exp2(alpha r') (r' = r*log2e); Rmax atomic.
// ---------------------------------------------------------------------------
__global__ __launch_bounds__(256) void k_prep(
    const float* __restrict__ hmat, const unsigned short* __restrict__ WTbf,
    const float* __restrict__ uLR, unsigned short* __restrict__ WhT,
    float* __restrict__ leftT, float* __restrict__ er, float* __restrict__ er2,
    unsigned int* __restrict__ Rmax)
{
    __shared__ float hs[16][132];
    __shared__ float us[128][8];
    const int tid = threadIdx.x;
    const int rowbase = blockIdx.x * 16;

    ((float4*)us)[tid] = ((const float4*)uLR)[tid];
#pragma unroll
    for (int p = 0; p < 8; ++p) {
        const int idx = p * 256 + tid;
        hs[idx >> 7][idx & 127] = hmat[(size_t)rowbase * IN_F + idx];
    }
    __syncthreads();

    const int lane = tid & 63, wv = tid >> 6;
    const int m16 = lane & 15, kg = lane >> 4;

    if (wv == 0) {
        const int row = lane >> 2, hd = lane & 3;
        float aL = 0.f, aR = 0.f;
#pragma unroll
        for (int k = 0; k < 128; k += 4) {
            const float4 hv = *(const float4*)&hs[row][k];
            aL = fmaf(hv.x, us[k][hd],   fmaf(hv.y, us[k+1][hd],   fmaf(hv.z, us[k+2][hd],   fmaf(hv.w, us[k+3][hd],   aL))));
            aR = fmaf(hv.x, us[k][hd+4], fmaf(hv.y, us[k+1][hd+4], fmaf(hv.z, us[k+2][hd+4], fmaf(hv.w, us[k+3][hd+4], aR))));
        }
        leftT[hd * NN + rowbase + row] = aL;
        const float rp = aR * LOG2E;
        er [hd * NN + rowbase + row] = exp2f(rp);
        er2[hd * NN + rowbase + row] = exp2f(ALPHA * rp);
        float mx = aR;
#pragma unroll
        for (int s = 4; s < 64; s <<= 1) mx = fmaxf(mx, __shfl_xor(mx, s, 64));
        if (lane < 4) atomicMax(&Rmax[hd], fmap(mx));
    }

    bf16x8 afr[4];
#pragma unroll
    for (int ks = 0; ks < 4; ++ks) {
        const float4 lo = *(const float4*)&hs[m16][ks * 32 + kg * 8];
        const float4 hi = *(const float4*)&hs[m16][ks * 32 + kg * 8 + 4];
        bf16x8 v;
        v[0] = (__bf16)lo.x; v[1] = (__bf16)lo.y; v[2] = (__bf16)lo.z; v[3] = (__bf16)lo.w;
        v[4] = (__bf16)hi.x; v[5] = (__bf16)hi.y; v[6] = (__bf16)hi.z; v[7] = (__bf16)hi.w;
        afr[ks] = v;
    }

#pragma unroll
    for (int nt0 = 0; nt0 < 4; ++nt0) {
        const int col = (wv * 4 + nt0) * 16 + m16;
        f32x4 acc = (f32x4){0.f, 0.f, 0.f, 0.f};
#pragma unroll
        for (int ks = 0; ks < 4; ++ks) {
            union { uint4 u; bf16x8 v; } B;
            B.u = *(const uint4*)(WTbf + (size_t)col * IN_F + ks * 32 + kg * 8);
            acc = __builtin_amdgcn_mfma_f32_16x16x32_bf16(afr[ks], B.v, acc, 0, 0, 0);
        }
#pragma unroll
        for (int i = 0; i < 4; ++i)
            WhT[(size_t)col * NN + rowbase + kg * 4 + i] = bfbits(acc[i]);
    }
}

// ---------------------------------------------------------------------------
// K3: attention partials — BARRIER-FREE, NO LDS STAGING. Grid 2048 x 256:
// block = 16 rows x 1 head x j-half; wave = independent 512-j chunk (16 tiles
// of 32 j). All operands (B rows, er/er2, mask word) read straight from
// L2 into registers as plain loads; occupancy hides latency. Factored exp
// (no transcendentals in loop), ones-MFMA denominator. LDS only for the
// final 4-wave combine. Partial outputs; k_fin combines jh halves.
// ---------------------------------------------------------------------------
__global__ __launch_bounds__(256, 4) void k_attn(
    const unsigned* __restrict__ maskT,       // [128][4096]
    const unsigned short* __restrict__ WhT,   // [256][4096]
    const float* __restrict__ leftT,
    const float* __restrict__ er,             // [4][4096]
    const float* __restrict__ er2,            // [4][4096]
    const unsigned int* __restrict__ Rmax,
    float* __restrict__ out,                  // jh=0 numerator partial
    float* __restrict__ num1,                 // jh=1 numerator partial
    float* __restrict__ den)                  // [2][4][4096]
{
    __shared__ float comb[3][64][20];

    const int tid = threadIdx.x;
    const int lane = tid & 63;
    const int wv = tid >> 6;            // 0..3: j-quarter of this half
    const int jh = blockIdx.x & 1;
    const int hd = (blockIdx.x >> 1) & 3;
    const int rowbase = (blockIdx.x >> 3) * 16;
    const int m = lane & 15;
    const int kg = lane >> 4;
    const int sh = kg * 8;
    const int jbase = jh * 2048 + wv * 512;

    // factored-exp constants
    const float rmx = funmap(Rmax[hd]);
    const float lf = leftT[hd * NN + rowbase + m];
    const float x = lf + rmx;
    const float mp0 = fmaxf(x, ALPHA * x) * LOG2E;
    const float EL  = exp2f(fmaf(lf,         LOG2E, -mp0));
    const float EL2 = exp2f(fmaf(lf * ALPHA, LOG2E, -mp0));
    const f32x2 ELv  = (f32x2){EL,  EL};
    const f32x2 EL2v = (f32x2){EL2, EL2};

    bf16x8 ONE8;
#pragma unroll
    for (int i = 0; i < 8; ++i) ONE8[i] = (__bf16)1.0f;

    // direct-L2 pointers
    const unsigned short* __restrict__ bp0 = WhT + (size_t)(hd * 64 +  0 + m) * NN + jbase + kg * 8;
    const unsigned short* __restrict__ bp1 = WhT + (size_t)(hd * 64 + 16 + m) * NN + jbase + kg * 8;
    const unsigned short* __restrict__ bp2 = WhT + (size_t)(hd * 64 + 32 + m) * NN + jbase + kg * 8;
    const unsigned short* __restrict__ bp3 = WhT + (size_t)(hd * 64 + 48 + m) * NN + jbase + kg * 8;
    const float* __restrict__ ep  = er  + (size_t)hd * NN + jbase + kg * 8;
    const float* __restrict__ e2p = er2 + (size_t)hd * NN + jbase + kg * 8;
    const unsigned* __restrict__ mp = maskT + (size_t)(jbase >> 5) * NN + rowbase + m;

    f32x4 acc0 = (f32x4){0,0,0,0}, acc1 = acc0, acc2 = acc0, acc3 = acc0;
    f32x4 accL = (f32x4){0,0,0,0};

    union F4 { f32x4 v; f32x2 h[2]; };

#pragma unroll 4
    for (int t = 0; t < 16; ++t) {
        const int o = t * 32;
        const unsigned aw = mp[(size_t)t * NN] >> sh;
        F4 E0, E1, F0, F1;
        E0.v = *(const f32x4*)(ep  + o);
        E1.v = *(const f32x4*)(ep  + o + 4);
        F0.v = *(const f32x4*)(e2p + o);
        F1.v = *(const f32x4*)(e2p + o + 4);
        union { uint4 u; bf16x8 v; } B0, B1, B2, B3;
        B0.u = *(const uint4*)(bp0 + o);
        B1.u = *(const uint4*)(bp1 + o);
        B2.u = *(const uint4*)(bp2 + o);
        B3.u = *(const uint4*)(bp3 + o);

        const f32x2 epr[4] = { E0.h[0], E0.h[1], E1.h[0], E1.h[1] };
        const f32x2 fpr[4] = { F0.h[0], F0.h[1], F1.h[0], F1.h[1] };
        union { __bf16 b[8]; bf16x8 v; } Af;
#pragma unroll
        for (int e = 0; e < 4; ++e) {
            const f32x2 full = epr[e] * ELv;            // v_pk_mul_f32
            const f32x2 leak = fpr[e] * EL2v;           // v_pk_mul_f32
            float w0 = fmaxf(full.x, leak.x);           // lrelu via max
            float w1 = fmaxf(full.y, leak.y);
            const unsigned mk0 = (unsigned)(((int)(aw << (31 - 2*e)))     >> 31);
            const unsigned mk1 = (unsigned)(((int)(aw << (31 - (2*e+1)))) >> 31);
            w0 = __uint_as_float(__float_as_uint(w0) & mk0);
            w1 = __uint_as_float(__float_as_uint(w1) & mk1);
            Af.b[2*e]   = (__bf16)w0;
            Af.b[2*e+1] = (__bf16)w1;
        }
        acc0 = __builtin_amdgcn_mfma_f32_16x16x32_bf16(Af.v, B0.v, acc0, 0, 0, 0);
        acc1 = __builtin_amdgcn_mfma_f32_16x16x32_bf16(Af.v, B1.v, acc1, 0, 0, 0);
        acc2 = __builtin_amdgcn_mfma_f32_16x16x32_bf16(Af.v, B2.v, acc2, 0, 0, 0);
        acc3 = __builtin_amdgcn_mfma_f32_16x16x32_bf16(Af.v, B3.v, acc3, 0, 0, 0);
        accL = __builtin_amdgcn_mfma_f32_16x16x32_bf16(Af.v, ONE8, accL, 0, 0, 0);
    }

    // ---- combine across the 4 j-quarter waves ----
    if (wv > 0) {
        float* c = &comb[wv - 1][lane][0];
#pragma unroll
        for (int i = 0; i < 4; ++i) {
            c[ 0 + i] = acc0[i]; c[ 4 + i] = acc1[i];
            c[ 8 + i] = acc2[i]; c[12 + i] = acc3[i];
            c[16 + i] = accL[i];
        }
    }
    __syncthreads();
    if (wv == 0) {
#pragma unroll
        for (int pt = 0; pt < 3; ++pt) {
            const float* c = &comb[pt][lane][0];
#pragma unroll
            for (int i = 0; i < 4; ++i) {
                acc0[i] += c[ 0 + i]; acc1[i] += c[ 4 + i];
                acc2[i] += c[ 8 + i]; acc3[i] += c[12 + i];
                accL[i] += c[16 + i];
            }
        }
        float* numdst = jh ? num1 : out;
#pragma unroll
        for (int q = 0; q < 4; ++q) {
            const f32x4 A = (q == 0) ? acc0 : (q == 1) ? acc1 : (q == 2) ? acc2 : acc3;
            const int col = hd * 64 + q * 16 + m;
#pragma unroll
            for (int i = 0; i < 4; ++i) {
                const int r = kg * 4 + i;
                numdst[(size_t)(rowbase + r) * C_TOT + col] = A[i];
            }
        }
        if (m == 0) {
#pragma unroll
            for (int i = 0; i < 4; ++i)
                den[(size_t)jh * 4 * NN + hd * NN + rowbase + kg * 4 + i] = accL[i];
        }
    }
}

// ---------------------------------------------------------------------------
// K4: finalize — out = (n0 + n1) / (d0 + d1) + bias. Grid 1024 x 256.
// ---------------------------------------------------------------------------
__global__ __launch_bounds__(256) void k_fin(
    float* __restrict__ out, const float* __restrict__ num1,
    const float* __restrict__ den, const float* __restrict__ bias)
{
    const int idx = blockIdx.x * 256 + threadIdx.x;   // float4 index
    const int row = idx >> 6;
    const int c4 = (idx & 63) * 4;
    const int hd = c4 >> 6;
    const float d = den[hd * NN + row] + den[4 * NN + hd * NN + row];
    const float rd = 1.0f / d;
    const size_t off = (size_t)row * C_TOT + c4;
    float4 n = *(float4*)(out + off);
    const float4 n1 = *(const float4*)(num1 + off);
    const float4 bv = *(const float4*)(bias + c4);
    n.x = fmaf(n.x + n1.x, rd, bv.x);
    n.y = fmaf(n.y + n1.y, rd, bv.y);
    n.z = fmaf(n.z + n1.z, rd, bv.z);
    n.w = fmaf(n.w + n1.w, rd, bv.w);
    *(float4*)(out + off) = n;
}

extern "C" void kernel_launch(void* const* d_in, const int* in_sizes, int n_in,
                              void* d_out, int out_size, void* d_ws, size_t ws_size,
                              hipStream_t stream) {
    const float* hmat = (const float*)d_in[0];
    const int*   adj  = (const int*)d_in[1];
    const float* W    = (const float*)d_in[2];
    const float* a    = (const float*)d_in[3];
    const float* bias = (const float*)d_in[4];
    float* out = (float*)d_out;

    char* ws = (char*)d_ws;
    unsigned short* WhT  = (unsigned short*)(ws + 0x000000);   // 2MB + pad
    float* leftT         = (float*)(ws + 0x2A0000);            // 64KB
    unsigned short* WTbf = (unsigned short*)(ws + 0x2B0000);   // 64KB
    float* uLR           = (float*)(ws + 0x2C0000);            // 4KB
    unsigned int* Rmax   = (unsigned int*)(ws + 0x2C1000);     // 16B
    float* er            = (float*)(ws + 0x2C2000);            // 64KB
    float* er2           = (float*)(ws + 0x2D2000);            // 64KB
    unsigned* maskT      = (unsigned*)(ws + 0x300000);         // 2MB
    float* num1          = (float*)(ws + 0x500000);            // 4MB
    float* den           = (float*)(ws + 0x900000);            // 128KB

    hipLaunchKernelGGL(k_mask, dim3(1024), dim3(256), 0, stream,
                       adj, maskT, W, a, WTbf, uLR, Rmax);
    hipLaunchKernelGGL(k_prep, dim3(256),  dim3(256), 0, stream,
                       hmat, WTbf, uLR, WhT, leftT, er, er2, Rmax);
    hipLaunchKernelGGL(k_attn, dim3(2048), dim3(256), 0, stream,
                       maskT, WhT, leftT, er, er2, Rmax, out, num1, den);
    hipLaunchKernelGGL(k_fin,  dim3(1024), dim3(256), 0, stream,
                       out, num1, den, bias);
}